// Round 10
// baseline (568.891 us; speedup 1.0000x reference)
//
#include <hip/hip_runtime.h>

#define N_NODES 100000
#define N_EDGES 1600000
#define NGRAPH 64
#define NBIN 391        // ceil(100000/256) bins of 256 nodes (dst>>8)
#define EPB 6400        // edges per binning block
#define NBLK 250        // 250*6400 = 1.6M
#define CAPB 6144       // padded per-bin capacity (avg 4092, +32 sigma)
#define CAP 8192        // LDS capacity in k_csr
#define PSPLIT 8

typedef short s8v __attribute__((ext_vector_type(8)));
typedef float f4v __attribute__((ext_vector_type(4)));

__device__ __forceinline__ float bflo(unsigned u) { return __uint_as_float(u << 16); }
__device__ __forceinline__ float bfhi(unsigned u) { return __uint_as_float(u & 0xffff0000u); }
__device__ __forceinline__ unsigned short f2bf(float f) {
    unsigned u = __float_as_uint(f);
    u += 0x7fffu + ((u >> 16) & 1u);
    return (unsigned short)(u >> 16);
}
__device__ __forceinline__ float bf2f(unsigned short h) { return __uint_as_float(((unsigned)h) << 16); }
__device__ __forceinline__ unsigned pk(float lo, float hi) {
    return (unsigned)f2bf(lo) | ((unsigned)f2bf(hi) << 16);
}
__device__ __forceinline__ float ldv(const void* p, int i, int f32) {
    return f32 ? ((const float*)p)[i] : bf2f(((const unsigned short*)p)[i]);
}

// ---------------- setup: detect + bininit + graph bounds + classifier params ------
__global__ __launch_bounds__(256) void k_setup(const unsigned short* __restrict__ x,
                                               const int* __restrict__ ei,
                                               const int* __restrict__ batch,
                                               int* __restrict__ flags,
                                               int* __restrict__ binCur,
                                               int* __restrict__ gstart,
                                               float* __restrict__ pbuf,
                                               const void* b0, const void* bn0g, const void* bn0b,
                                               const void* b1, const void* bn1g, const void* bn1b,
                                               const void* b2, const void* bn2g, const void* bn2b,
                                               const void* b3) {
    __shared__ int cnt[3];
    int tid = threadIdx.x;
    if (tid < 3) cnt[tid] = 0;
    __syncthreads();
    unsigned short h = x[tid * 37];
    int e = (h >> 7) & 0xFF;
    if (e >= 100 && e <= 150) atomicAdd(&cnt[0], 1);
    if (ei[2 * (tid * 5000) + 1] == 0) atomicAdd(&cnt[1], 1);
    if (batch[2 * (tid * 193) + 1] == 0) atomicAdd(&cnt[2], 1);
    __syncthreads();
    int f = (cnt[0] == 256) ? 0 : 1;
    int b64 = (cnt[2] == 256) ? 1 : 0;
    if (tid == 0) {
        flags[0] = f;
        flags[1] = (cnt[1] == 256) ? 1 : 0;
        flags[2] = b64;
    }
    for (int i = tid; i < NBIN; i += 256) binCur[i] = i * CAPB;
    if (tid <= NGRAPH) {
        int g = tid, lo = 0, hi = N_NODES;
        while (lo < hi) {
            int mid = (lo + hi) >> 1;
            int v = b64 ? batch[2 * mid] : batch[mid];
            if (v < g) lo = mid + 1;
            else hi = mid;
        }
        gstart[g] = lo;
    }
    const float invs = rsqrtf(1.0f + 1e-5f);
    if (tid < 200) {
        float a = ldv(bn0g, tid, f) * invs;
        pbuf[tid] = a;
        pbuf[200 + tid] = ldv(b0, tid, f) * a + ldv(bn0b, tid, f);
    }
    if (tid < 100) {
        float a = ldv(bn1g, tid, f) * invs;
        pbuf[400 + tid] = a;
        pbuf[500 + tid] = ldv(b1, tid, f) * a + ldv(bn1b, tid, f);
    }
    if (tid < 50) {
        float a = ldv(bn2g, tid, f) * invs;
        pbuf[600 + tid] = a;
        pbuf[650 + tid] = ldv(b2, tid, f) * a + ldv(bn2b, tid, f);
    }
    if (tid < 10) pbuf[700 + tid] = ldv(b3, tid, f);
}

// ---------------- CSR build: padded bins ----------------
__global__ __launch_bounds__(256) void k_binfill(const int* __restrict__ ei,
                                                 int* __restrict__ binCur,
                                                 unsigned* __restrict__ staging,
                                                 const int* __restrict__ flags) {
    __shared__ int cnt[NBIN];
    __shared__ int lofs[NBIN];
    __shared__ int curL[NBIN];
    __shared__ int basg[NBIN];
    __shared__ int sA[512], sB[512];
    __shared__ unsigned ebuf[EPB];
    int tid = threadIdx.x;
    int i64 = flags[1];
    int base = blockIdx.x * EPB;
    for (int i = tid; i < NBIN; i += 256) cnt[i] = 0;
    __syncthreads();
    for (int k = 0; k < EPB / 256; ++k) {
        int e = base + k * 256 + tid;
        int d = i64 ? ei[2 * (N_EDGES + e)] : ei[N_EDGES + e];
        if ((unsigned)d < N_NODES) atomicAdd(&cnt[d >> 8], 1);
    }
    __syncthreads();
    for (int k = tid; k < 512; k += 256) sA[k] = (k < NBIN) ? cnt[k] : 0;
    __syncthreads();
    int* src = sA;
    int* dst = sB;
    for (int off = 1; off < 512; off <<= 1) {
        for (int k = tid; k < 512; k += 256)
            dst[k] = src[k] + ((k >= off) ? src[k - off] : 0);
        __syncthreads();
        int* t = src; src = dst; dst = t;
    }
    for (int i = tid; i < NBIN; i += 256) {
        int excl = src[i] - cnt[i];
        lofs[i] = excl;
        curL[i] = excl;
        basg[i] = cnt[i] ? atomicAdd(&binCur[i], cnt[i]) : 0;
    }
    __syncthreads();
    for (int k = 0; k < EPB / 256; ++k) {
        int e = base + k * 256 + tid;
        int s = i64 ? ei[2 * e] : ei[e];
        int d = i64 ? ei[2 * (N_EDGES + e)] : ei[N_EDGES + e];
        if ((unsigned)d < N_NODES) {
            s = min(max(s, 0), N_NODES - 1);
            int p = atomicAdd(&curL[d >> 8], 1);
            ebuf[p] = ((unsigned)(d & 255) << 20) | (unsigned)s;
        }
    }
    __syncthreads();
    int wid = tid >> 6, lane = tid & 63;
    for (int b = wid; b < NBIN; b += 4) {
        int n = cnt[b], lo = lofs[b], go = basg[b];
        int cap = (b + 1) * CAPB;
        for (int l = lane; l < n; l += 64)
            if (go + l < cap) staging[go + l] = ebuf[lo + l];
    }
}

// per-bin sub-CSR in LDS + fused prescale y = dinv*x for this bin's nodes
__global__ __launch_bounds__(256) void k_csr(const unsigned* __restrict__ staging,
                                             const int* __restrict__ binCur,
                                             int* __restrict__ rsA, int* __restrict__ reA,
                                             float* __restrict__ dinv,
                                             int* __restrict__ colidx,
                                             const void* __restrict__ x,
                                             unsigned* __restrict__ ybuf,
                                             const int* __restrict__ flags) {
    __shared__ int deg[256];
    __shared__ int s[256];
    __shared__ int cur[256];
    __shared__ unsigned ebuf[CAP];
    __shared__ int colbuf[CAP];
    int b = blockIdx.x, tid = threadIdx.x;
    int n0 = b << 8;
    int nend = min(256, N_NODES - n0);
    int runStart = b * CAPB;
    int runLen = min(binCur[b] - runStart, CAPB);
    deg[tid] = 0;
    __syncthreads();
    for (int i = tid; i < runLen; i += 256) {
        unsigned e = staging[runStart + i];
        ebuf[i] = e;
        atomicAdd(&deg[e >> 20], 1);
    }
    __syncthreads();
    int myDeg = deg[tid];
    s[tid] = myDeg;
    __syncthreads();
    for (int off = 1; off < 256; off <<= 1) {
        int x2 = (tid >= off) ? s[tid - off] : 0;
        __syncthreads();
        s[tid] += x2;
        __syncthreads();
    }
    int incl = s[tid];
    if (tid < nend) {
        rsA[n0 + tid] = runStart + incl - myDeg;
        reA[n0 + tid] = runStart + incl;
        dinv[n0 + tid] = rsqrtf((float)myDeg + 1.0f);
    }
    cur[tid] = incl - myDeg;
    __syncthreads();
    for (int i = tid; i < runLen; i += 256) {
        unsigned e = ebuf[i];
        int p = atomicAdd(&cur[e >> 20], 1);
        colbuf[p] = (int)(e & 0xFFFFF);
    }
    __syncthreads();
    for (int i = tid; i < runLen; i += 256) colidx[runStart + i] = colbuf[i];
    // fused prescale for this bin's 256 nodes
    int f32 = flags[0];
    int prow = tid >> 6, ppair = tid & 63;
    for (int it = 0; it < 64; ++it) {
        int rl = it * 4 + prow;
        int r = n0 + rl;
        if (r < N_NODES) {
            float di = rsqrtf((float)deg[rl] + 1.0f);
            float lo, hi;
            if (f32) {
                float2 u = ((const float2*)x)[(size_t)r * 64 + ppair];
                lo = u.x; hi = u.y;
            } else {
                unsigned u = ((const unsigned*)x)[(size_t)r * 64 + ppair];
                lo = bflo(u); hi = bfhi(u);
            }
            ybuf[(size_t)r * 64 + ppair] = pk(di * lo, di * hi);
        }
    }
}

// ---------------- unified aggregation: gather-sum over bf16 rows ----------------
__global__ __launch_bounds__(256) void k_agg(const uint4* __restrict__ xs,
                                             const int* __restrict__ rsA,
                                             const int* __restrict__ reA,
                                             const float* __restrict__ dinv,
                                             unsigned* __restrict__ out, int mode,
                                             const int* __restrict__ col) {
    int lane = threadIdx.x & 63;
    int node = blockIdx.x * 4 + (threadIdx.x >> 6);
    int glane = lane & 15, grp = lane >> 4;
    int rs = rsA[node], re = reA[node];
    int deg = re - rs;
    float a[8];
    #pragma unroll
    for (int i = 0; i < 8; ++i) a[i] = 0.f;
    uint4 selfu = make_uint4(0u, 0u, 0u, 0u);
    if (mode == 0) selfu = xs[(size_t)node * 16 + glane];

    int efull = rs + (deg & ~15);
    for (int base = rs; base < efull; base += 16) {
        int j0 = col[base + grp * 4 + 0];
        int j1 = col[base + grp * 4 + 1];
        int j2 = col[base + grp * 4 + 2];
        int j3 = col[base + grp * 4 + 3];
        uint4 u0 = xs[(size_t)j0 * 16 + glane];
        uint4 u1 = xs[(size_t)j1 * 16 + glane];
        uint4 u2 = xs[(size_t)j2 * 16 + glane];
        uint4 u3 = xs[(size_t)j3 * 16 + glane];
        a[0] += bflo(u0.x) + bflo(u1.x) + bflo(u2.x) + bflo(u3.x);
        a[1] += bfhi(u0.x) + bfhi(u1.x) + bfhi(u2.x) + bfhi(u3.x);
        a[2] += bflo(u0.y) + bflo(u1.y) + bflo(u2.y) + bflo(u3.y);
        a[3] += bfhi(u0.y) + bfhi(u1.y) + bfhi(u2.y) + bfhi(u3.y);
        a[4] += bflo(u0.z) + bflo(u1.z) + bflo(u2.z) + bflo(u3.z);
        a[5] += bfhi(u0.z) + bfhi(u1.z) + bfhi(u2.z) + bfhi(u3.z);
        a[6] += bflo(u0.w) + bflo(u1.w) + bflo(u2.w) + bflo(u3.w);
        a[7] += bfhi(u0.w) + bfhi(u1.w) + bfhi(u2.w) + bfhi(u3.w);
    }
    if (efull < re) {
        int j[4];
        float w[4];
        #pragma unroll
        for (int k = 0; k < 4; ++k) {
            int ee = efull + grp * 4 + k;
            bool v = ee < re;
            j[k] = col[v ? ee : re - 1];
            w[k] = v ? 1.f : 0.f;
        }
        uint4 u0 = xs[(size_t)j[0] * 16 + glane];
        uint4 u1 = xs[(size_t)j[1] * 16 + glane];
        uint4 u2 = xs[(size_t)j[2] * 16 + glane];
        uint4 u3 = xs[(size_t)j[3] * 16 + glane];
        a[0] += w[0] * bflo(u0.x) + w[1] * bflo(u1.x) + w[2] * bflo(u2.x) + w[3] * bflo(u3.x);
        a[1] += w[0] * bfhi(u0.x) + w[1] * bfhi(u1.x) + w[2] * bfhi(u2.x) + w[3] * bfhi(u3.x);
        a[2] += w[0] * bflo(u0.y) + w[1] * bflo(u1.y) + w[2] * bflo(u2.y) + w[3] * bflo(u3.y);
        a[3] += w[0] * bfhi(u0.y) + w[1] * bfhi(u1.y) + w[2] * bfhi(u2.y) + w[3] * bfhi(u3.y);
        a[4] += w[0] * bflo(u0.z) + w[1] * bflo(u1.z) + w[2] * bflo(u2.z) + w[3] * bflo(u3.z);
        a[5] += w[0] * bfhi(u0.z) + w[1] * bfhi(u1.z) + w[2] * bfhi(u2.z) + w[3] * bfhi(u3.z);
        a[6] += w[0] * bflo(u0.w) + w[1] * bflo(u1.w) + w[2] * bflo(u2.w) + w[3] * bflo(u3.w);
        a[7] += w[0] * bfhi(u0.w) + w[1] * bfhi(u1.w) + w[2] * bfhi(u2.w) + w[3] * bfhi(u3.w);
    }
    #pragma unroll
    for (int i = 0; i < 8; ++i) {
        float v = a[i];
        v += __shfl_xor(v, 16, 64);
        v += __shfl_xor(v, 32, 64);
        a[i] = v;
    }
    if (mode == 0) {
        float di = dinv[node];
        a[0] = di * (a[0] + bflo(selfu.x)); a[1] = di * (a[1] + bfhi(selfu.x));
        a[2] = di * (a[2] + bflo(selfu.y)); a[3] = di * (a[3] + bfhi(selfu.y));
        a[4] = di * (a[4] + bflo(selfu.z)); a[5] = di * (a[5] + bfhi(selfu.z));
        a[6] = di * (a[6] + bflo(selfu.w)); a[7] = di * (a[7] + bfhi(selfu.w));
    } else {
        float s = 1.0f / fmaxf((float)deg, 1.0f);
        #pragma unroll
        for (int i = 0; i < 8; ++i) a[i] *= s;
    }
    if (grp == 0) {
        uint4 o;
        o.x = pk(a[0], a[1]); o.y = pk(a[2], a[3]);
        o.z = pk(a[4], a[5]); o.w = pk(a[6], a[7]);
        *(uint4*)(out + (size_t)node * 64 + glane * 4) = o;
    }
}

// ---------------- MFMA GEMM ----------------
template <int DUAL>
__global__ __launch_bounds__(256) void k_gemm(const unsigned short* A0,
                                              const void* __restrict__ W0,
                                              const unsigned short* __restrict__ A1,
                                              const void* __restrict__ W1,
                                              const void* __restrict__ bias,
                                              unsigned short* out,
                                              const int* __restrict__ flags) {
    __shared__ __align__(16) unsigned short As[64][136];
    __shared__ __align__(16) unsigned short Ws[128][136];
    int f32 = flags[0];
    int tid = threadIdx.x;
    int lane = tid & 63;
    int rowbase = blockIdx.x * 64;
    int lr = lane & 15, q = lane >> 4;
    int m0 = (tid >> 6) * 16;

    f4v acc[8];
    #pragma unroll
    for (int t = 0; t < 8; ++t) acc[t] = (f4v){0.f, 0.f, 0.f, 0.f};

    #pragma unroll
    for (int p = 0; p < (DUAL ? 2 : 1); ++p) {
        const unsigned short* Ap = p ? A1 : A0;
        const void* Wp = p ? W1 : W0;
        if (p) __syncthreads();
        #pragma unroll
        for (int it = 0; it < 4; ++it) {
            int chunk = tid + it * 256;
            int r = chunk >> 4, c8 = (chunk & 15) * 8;
            int grow = rowbase + r;
            uint4 v = make_uint4(0u, 0u, 0u, 0u);
            if (grow < N_NODES) v = *(const uint4*)(Ap + (size_t)grow * 128 + c8);
            *(uint4*)&As[r][c8] = v;
        }
        if (!f32) {
            const unsigned short* Wf = (const unsigned short*)Wp;
            #pragma unroll
            for (int it = 0; it < 8; ++it) {
                int chunk = tid + it * 256;
                int r = chunk >> 4, c8 = (chunk & 15) * 8;
                *(uint4*)&Ws[r][c8] = *(const uint4*)(Wf + r * 128 + c8);
            }
        } else {
            const float* Wf = (const float*)Wp;
            #pragma unroll
            for (int it = 0; it < 16; ++it) {
                int chunk = tid + it * 256;
                int r = chunk >> 5, c4 = (chunk & 31) * 4;
                float4 v = *(const float4*)(Wf + r * 128 + c4);
                unsigned lo = (unsigned)f2bf(v.x) | ((unsigned)f2bf(v.y) << 16);
                unsigned hi = (unsigned)f2bf(v.z) | ((unsigned)f2bf(v.w) << 16);
                *(uint2*)&Ws[r][c4] = make_uint2(lo, hi);
            }
        }
        __syncthreads();
        #pragma unroll
        for (int k = 0; k < 4; ++k) {
            s8v a = *(const s8v*)&As[m0 + lr][k * 32 + q * 8];
            #pragma unroll
            for (int t = 0; t < 8; ++t) {
                s8v b = *(const s8v*)&Ws[t * 16 + lr][k * 32 + q * 8];
                acc[t] = __builtin_amdgcn_mfma_f32_16x16x32_bf16(a, b, acc[t], 0, 0, 0);
            }
        }
    }
    #pragma unroll
    for (int t = 0; t < 8; ++t) {
        int o = t * 16 + lr;
        float bv = ldv(bias, o, f32);
        #pragma unroll
        for (int j = 0; j < 4; ++j) {
            int m = rowbase + m0 + q * 4 + j;
            if (m < N_NODES) out[(size_t)m * 128 + o] = f2bf(acc[t][j] + bv);
        }
    }
}

// ---------------- fused pool + classifier + softmax: one block per graph ---------
__global__ __launch_bounds__(512) void k_poolclf(const unsigned* __restrict__ h,
                                                 const int* __restrict__ gstart,
                                                 const float* __restrict__ pbuf,
                                                 const void* w0, const void* w1,
                                                 const void* w2, const void* w3,
                                                 void* outv, const int* __restrict__ flags) {
    __shared__ float part[8][128];
    __shared__ float gmean[128];
    __shared__ float h1s[200];
    __shared__ float h2s[100];
    __shared__ float h3s[50];
    __shared__ float lg[10];
    int g = blockIdx.x, t = threadIdx.x;
    int wave = t >> 6, lane = t & 63;
    int f = flags[0];
    int s0 = gstart[g], s1 = gstart[g + 1];
    float a0 = 0.f, a1 = 0.f;
    for (int r = s0 + wave * 4; r < s1; r += 32) {
        #pragma unroll
        for (int k = 0; k < 4; ++k) {
            int rr = r + k;
            if (rr < s1) {
                unsigned u = h[(size_t)rr * 64 + lane];
                a0 += bflo(u);
                a1 += bfhi(u);
            }
        }
    }
    part[wave][2 * lane] = a0;
    part[wave][2 * lane + 1] = a1;
    __syncthreads();
    if (t < 128) {
        float s = 0.f;
        #pragma unroll
        for (int k = 0; k < 8; ++k) s += part[k][t];
        gmean[t] = s / fmaxf((float)(s1 - s0), 1.0f);
    }
    __syncthreads();
    // L0: 128 -> 200
    if (t < 200) {
        float s = 0.f;
        if (f) {
            const float4* wr = (const float4*)w0 + t * 32;
            #pragma unroll
            for (int k = 0; k < 32; ++k) {
                float4 v = wr[k];
                s += v.x * gmean[4 * k] + v.y * gmean[4 * k + 1] +
                     v.z * gmean[4 * k + 2] + v.w * gmean[4 * k + 3];
            }
        } else {
            const unsigned* wr = (const unsigned*)w0 + t * 64;
            for (int k = 0; k < 64; ++k) {
                unsigned u = wr[k];
                s += bflo(u) * gmean[2 * k] + bfhi(u) * gmean[2 * k + 1];
            }
        }
        h1s[t] = tanhf(s * pbuf[t] + pbuf[200 + t]);
    }
    __syncthreads();
    // L1: 200 -> 100
    if (t < 100) {
        float s = 0.f;
        if (f) {
            const float4* wr = (const float4*)w1 + t * 50;
            #pragma unroll
            for (int k = 0; k < 50; ++k) {
                float4 v = wr[k];
                s += v.x * h1s[4 * k] + v.y * h1s[4 * k + 1] +
                     v.z * h1s[4 * k + 2] + v.w * h1s[4 * k + 3];
            }
        } else {
            const unsigned* wr = (const unsigned*)w1 + t * 100;
            for (int k = 0; k < 100; ++k) {
                unsigned u = wr[k];
                s += bflo(u) * h1s[2 * k] + bfhi(u) * h1s[2 * k + 1];
            }
        }
        h2s[t] = tanhf(s * pbuf[400 + t] + pbuf[500 + t]);
    }
    __syncthreads();
    // L2: 100 -> 50
    if (t < 50) {
        float s = 0.f;
        if (f) {
            const float4* wr = (const float4*)w2 + t * 25;
            #pragma unroll
            for (int k = 0; k < 25; ++k) {
                float4 v = wr[k];
                s += v.x * h2s[4 * k] + v.y * h2s[4 * k + 1] +
                     v.z * h2s[4 * k + 2] + v.w * h2s[4 * k + 3];
            }
        } else {
            const unsigned* wr = (const unsigned*)w2 + t * 50;
            for (int k = 0; k < 50; ++k) {
                unsigned u = wr[k];
                s += bflo(u) * h2s[2 * k] + bfhi(u) * h2s[2 * k + 1];
            }
        }
        h3s[t] = tanhf(s * pbuf[600 + t] + pbuf[650 + t]);
    }
    __syncthreads();
    // L3 logits: 50 -> 10
    if (t < 10) {
        float s = 0.f;
        if (f) {
            const float* wr = (const float*)w3 + t * 50;
            for (int k = 0; k < 50; ++k) s += wr[k] * h3s[k];
        } else {
            const unsigned* wr = (const unsigned*)((const unsigned short*)w3 + t * 50);
            for (int k = 0; k < 25; ++k) {
                unsigned u = wr[k];
                s += bflo(u) * h3s[2 * k] + bfhi(u) * h3s[2 * k + 1];
            }
        }
        lg[t] = s + pbuf[700 + t];
    }
    __syncthreads();
    if (t == 0) {
        float mx = -1e30f;
        #pragma unroll
        for (int c = 0; c < 10; ++c) mx = fmaxf(mx, lg[c]);
        float sum = 0.f;
        float ex[10];
        #pragma unroll
        for (int c = 0; c < 10; ++c) {
            ex[c] = __expf(lg[c] - mx);
            sum += ex[c];
        }
        float inv = 1.0f / sum;
        #pragma unroll
        for (int c = 0; c < 10; ++c) {
            float v = ex[c] * inv;
            if (f) ((float*)outv)[g * 10 + c] = v;
            else ((unsigned short*)outv)[g * 10 + c] = f2bf(v);
        }
    }
}

extern "C" void kernel_launch(void* const* d_in, const int* in_sizes, int n_in,
                              void* d_out, int out_size, void* d_ws, size_t ws_size,
                              hipStream_t stream) {
    const unsigned short* x16 = (const unsigned short*)d_in[0];
    const int* ei = (const int*)d_in[1];
    const int* batch = (const int*)d_in[2];

    char* ws = (char*)d_ws;
    size_t off = 0;
    auto alloc = [&](size_t bytes) {
        size_t r = off;
        off = (off + bytes + 255) & ~(size_t)255;
        return r;
    };
    int* flags = (int*)(ws + alloc(256));
    int* rsA = (int*)(ws + alloc((size_t)N_NODES * 4));
    int* reA = (int*)(ws + alloc((size_t)N_NODES * 4));
    int* colidx = (int*)(ws + alloc((size_t)NBIN * CAPB * 4));
    float* dinv = (float*)(ws + alloc((size_t)N_NODES * 4));
    int* binCur = (int*)(ws + alloc(NBIN * 4));
    int* gstart = (int*)(ws + alloc((NGRAPH + 1) * 4));
    float* pbuf = (float*)(ws + alloc(710 * 4));
    unsigned short* bufA = (unsigned short*)(ws + alloc((size_t)N_NODES * 128 * 2));
    unsigned short* bufB = (unsigned short*)(ws + alloc((size_t)N_NODES * 128 * 2));
    unsigned* staging = (unsigned*)bufA;  // 9.6 MB < 25.6 MB; consumed before k_agg writes bufA

    k_setup<<<1, 256, 0, stream>>>(x16, ei, batch, flags, binCur, gstart, pbuf,
                                   d_in[12], d_in[19], d_in[20],
                                   d_in[14], d_in[21], d_in[22],
                                   d_in[16], d_in[23], d_in[24], d_in[18]);

    // padded-bin CSR build + fused prescale (y = dinv*x -> bufB)
    k_binfill<<<NBLK, 256, 0, stream>>>(ei, binCur, staging, flags);
    k_csr<<<NBIN, 256, 0, stream>>>(staging, binCur, rsA, reA, dinv, colidx,
                                    (const void*)x16, (unsigned*)bufB, flags);

    // GCN: agg-sum(y)+self, scale dinv -> bufA; gemm in-place
    k_agg<<<N_NODES / 4, 256, 0, stream>>>((const uint4*)bufB, rsA, reA, dinv,
                                           (unsigned*)bufA, 0, colidx);
    k_gemm<0><<<(N_NODES + 63) / 64, 256, 0, stream>>>(bufA, d_in[3], nullptr, nullptr, d_in[4],
                                                       bufA, flags);
    // SAGE1
    k_agg<<<N_NODES / 4, 256, 0, stream>>>((const uint4*)bufA, rsA, reA, dinv,
                                           (unsigned*)bufB, 1, colidx);
    k_gemm<1><<<(N_NODES + 63) / 64, 256, 0, stream>>>(bufB, d_in[5], bufA, d_in[7], d_in[6],
                                                       bufB, flags);
    // SAGE2
    k_agg<<<N_NODES / 4, 256, 0, stream>>>((const uint4*)bufB, rsA, reA, dinv,
                                           (unsigned*)bufA, 1, colidx);
    k_gemm<1><<<(N_NODES + 63) / 64, 256, 0, stream>>>(bufA, d_in[8], bufB, d_in[10], d_in[9],
                                                       bufA, flags);
    // fused pool + classifier
    k_poolclf<<<NGRAPH, 512, 0, stream>>>((const unsigned*)bufA, gstart, pbuf,
                                          d_in[11], d_in[13], d_in[15], d_in[17],
                                          d_out, flags);
}

// Round 11
// 546.154 us; speedup vs baseline: 1.0416x; 1.0416x over previous
//
#include <hip/hip_runtime.h>

#define N_NODES 100000
#define N_EDGES 1600000
#define NGRAPH 64
#define NBIN 391        // ceil(100000/256) bins of 256 nodes (dst>>8)
#define EPB 6400        // edges per binning block
#define NBLK 250        // 250*6400 = 1.6M
#define CAPB 6144       // padded per-bin capacity (avg 4092, +32 sigma)
#define CAP 8192        // LDS capacity in k_csr
#define PSPLIT 8        // pool slices per graph

typedef short s8v __attribute__((ext_vector_type(8)));
typedef float f4v __attribute__((ext_vector_type(4)));

__device__ __forceinline__ float bflo(unsigned u) { return __uint_as_float(u << 16); }
__device__ __forceinline__ float bfhi(unsigned u) { return __uint_as_float(u & 0xffff0000u); }
__device__ __forceinline__ unsigned short f2bf(float f) {
    unsigned u = __float_as_uint(f);
    u += 0x7fffu + ((u >> 16) & 1u);
    return (unsigned short)(u >> 16);
}
__device__ __forceinline__ float bf2f(unsigned short h) { return __uint_as_float(((unsigned)h) << 16); }
__device__ __forceinline__ unsigned pk(float lo, float hi) {
    return (unsigned)f2bf(lo) | ((unsigned)f2bf(hi) << 16);
}
__device__ __forceinline__ float ldv(const void* p, int i, int f32) {
    return f32 ? ((const float*)p)[i] : bf2f(((const unsigned short*)p)[i]);
}

// ---------------- setup: detect + bininit + graph bounds + classifier params ------
__global__ __launch_bounds__(256) void k_setup(const unsigned short* __restrict__ x,
                                               const int* __restrict__ ei,
                                               const int* __restrict__ batch,
                                               int* __restrict__ flags,
                                               int* __restrict__ binCur,
                                               int* __restrict__ gstart,
                                               float* __restrict__ pbuf,
                                               const void* b0, const void* bn0g, const void* bn0b,
                                               const void* b1, const void* bn1g, const void* bn1b,
                                               const void* b2, const void* bn2g, const void* bn2b,
                                               const void* b3) {
    __shared__ int cnt[3];
    int tid = threadIdx.x;
    if (tid < 3) cnt[tid] = 0;
    __syncthreads();
    unsigned short h = x[tid * 37];
    int e = (h >> 7) & 0xFF;
    if (e >= 100 && e <= 150) atomicAdd(&cnt[0], 1);
    if (ei[2 * (tid * 5000) + 1] == 0) atomicAdd(&cnt[1], 1);
    if (batch[2 * (tid * 193) + 1] == 0) atomicAdd(&cnt[2], 1);
    __syncthreads();
    int f = (cnt[0] == 256) ? 0 : 1;
    int b64 = (cnt[2] == 256) ? 1 : 0;
    if (tid == 0) {
        flags[0] = f;
        flags[1] = (cnt[1] == 256) ? 1 : 0;
        flags[2] = b64;
    }
    for (int i = tid; i < NBIN; i += 256) binCur[i] = i * CAPB;
    if (tid <= NGRAPH) {
        int g = tid, lo = 0, hi = N_NODES;
        while (lo < hi) {
            int mid = (lo + hi) >> 1;
            int v = b64 ? batch[2 * mid] : batch[mid];
            if (v < g) lo = mid + 1;
            else hi = mid;
        }
        gstart[g] = lo;
    }
    const float invs = rsqrtf(1.0f + 1e-5f);
    if (tid < 200) {
        float a = ldv(bn0g, tid, f) * invs;
        pbuf[tid] = a;
        pbuf[200 + tid] = ldv(b0, tid, f) * a + ldv(bn0b, tid, f);
    }
    if (tid < 100) {
        float a = ldv(bn1g, tid, f) * invs;
        pbuf[400 + tid] = a;
        pbuf[500 + tid] = ldv(b1, tid, f) * a + ldv(bn1b, tid, f);
    }
    if (tid < 50) {
        float a = ldv(bn2g, tid, f) * invs;
        pbuf[600 + tid] = a;
        pbuf[650 + tid] = ldv(b2, tid, f) * a + ldv(bn2b, tid, f);
    }
    if (tid < 10) pbuf[700 + tid] = ldv(b3, tid, f);
}

// ---------------- CSR build: padded bins ----------------
__global__ __launch_bounds__(256) void k_binfill(const int* __restrict__ ei,
                                                 int* __restrict__ binCur,
                                                 unsigned* __restrict__ staging,
                                                 const int* __restrict__ flags) {
    __shared__ int cnt[NBIN];
    __shared__ int lofs[NBIN];
    __shared__ int curL[NBIN];
    __shared__ int basg[NBIN];
    __shared__ int sA[512], sB[512];
    __shared__ unsigned ebuf[EPB];
    int tid = threadIdx.x;
    int i64 = flags[1];
    int base = blockIdx.x * EPB;
    for (int i = tid; i < NBIN; i += 256) cnt[i] = 0;
    __syncthreads();
    for (int k = 0; k < EPB / 256; ++k) {
        int e = base + k * 256 + tid;
        int d = i64 ? ei[2 * (N_EDGES + e)] : ei[N_EDGES + e];
        if ((unsigned)d < N_NODES) atomicAdd(&cnt[d >> 8], 1);
    }
    __syncthreads();
    for (int k = tid; k < 512; k += 256) sA[k] = (k < NBIN) ? cnt[k] : 0;
    __syncthreads();
    int* src = sA;
    int* dst = sB;
    for (int off = 1; off < 512; off <<= 1) {
        for (int k = tid; k < 512; k += 256)
            dst[k] = src[k] + ((k >= off) ? src[k - off] : 0);
        __syncthreads();
        int* t = src; src = dst; dst = t;
    }
    for (int i = tid; i < NBIN; i += 256) {
        int excl = src[i] - cnt[i];
        lofs[i] = excl;
        curL[i] = excl;
        basg[i] = cnt[i] ? atomicAdd(&binCur[i], cnt[i]) : 0;
    }
    __syncthreads();
    for (int k = 0; k < EPB / 256; ++k) {
        int e = base + k * 256 + tid;
        int s = i64 ? ei[2 * e] : ei[e];
        int d = i64 ? ei[2 * (N_EDGES + e)] : ei[N_EDGES + e];
        if ((unsigned)d < N_NODES) {
            s = min(max(s, 0), N_NODES - 1);
            int p = atomicAdd(&curL[d >> 8], 1);
            ebuf[p] = ((unsigned)(d & 255) << 20) | (unsigned)s;
        }
    }
    __syncthreads();
    int wid = tid >> 6, lane = tid & 63;
    for (int b = wid; b < NBIN; b += 4) {
        int n = cnt[b], lo = lofs[b], go = basg[b];
        int cap = (b + 1) * CAPB;
        for (int l = lane; l < n; l += 64)
            if (go + l < cap) staging[go + l] = ebuf[lo + l];
    }
}

// per-bin sub-CSR in LDS + fused prescale y = dinv*x for this bin's nodes
__global__ __launch_bounds__(256) void k_csr(const unsigned* __restrict__ staging,
                                             const int* __restrict__ binCur,
                                             int* __restrict__ rsA, int* __restrict__ reA,
                                             float* __restrict__ dinv,
                                             int* __restrict__ colidx,
                                             const void* __restrict__ x,
                                             unsigned* __restrict__ ybuf,
                                             const int* __restrict__ flags) {
    __shared__ int deg[256];
    __shared__ int s[256];
    __shared__ int cur[256];
    __shared__ unsigned ebuf[CAP];
    __shared__ int colbuf[CAP];
    int b = blockIdx.x, tid = threadIdx.x;
    int n0 = b << 8;
    int nend = min(256, N_NODES - n0);
    int runStart = b * CAPB;
    int runLen = min(binCur[b] - runStart, CAPB);
    deg[tid] = 0;
    __syncthreads();
    for (int i = tid; i < runLen; i += 256) {
        unsigned e = staging[runStart + i];
        ebuf[i] = e;
        atomicAdd(&deg[e >> 20], 1);
    }
    __syncthreads();
    int myDeg = deg[tid];
    s[tid] = myDeg;
    __syncthreads();
    for (int off = 1; off < 256; off <<= 1) {
        int x2 = (tid >= off) ? s[tid - off] : 0;
        __syncthreads();
        s[tid] += x2;
        __syncthreads();
    }
    int incl = s[tid];
    if (tid < nend) {
        rsA[n0 + tid] = runStart + incl - myDeg;
        reA[n0 + tid] = runStart + incl;
        dinv[n0 + tid] = rsqrtf((float)myDeg + 1.0f);
    }
    cur[tid] = incl - myDeg;
    __syncthreads();
    for (int i = tid; i < runLen; i += 256) {
        unsigned e = ebuf[i];
        int p = atomicAdd(&cur[e >> 20], 1);
        colbuf[p] = (int)(e & 0xFFFFF);
    }
    __syncthreads();
    for (int i = tid; i < runLen; i += 256) colidx[runStart + i] = colbuf[i];
    // fused prescale for this bin's 256 nodes
    int f32 = flags[0];
    int prow = tid >> 6, ppair = tid & 63;
    for (int it = 0; it < 64; ++it) {
        int rl = it * 4 + prow;
        int r = n0 + rl;
        if (r < N_NODES) {
            float di = rsqrtf((float)deg[rl] + 1.0f);
            float lo, hi;
            if (f32) {
                float2 u = ((const float2*)x)[(size_t)r * 64 + ppair];
                lo = u.x; hi = u.y;
            } else {
                unsigned u = ((const unsigned*)x)[(size_t)r * 64 + ppair];
                lo = bflo(u); hi = bfhi(u);
            }
            ybuf[(size_t)r * 64 + ppair] = pk(di * lo, di * hi);
        }
    }
}

// ---------------- unified aggregation: gather-sum over bf16 rows ----------------
__global__ __launch_bounds__(256) void k_agg(const uint4* __restrict__ xs,
                                             const int* __restrict__ rsA,
                                             const int* __restrict__ reA,
                                             const float* __restrict__ dinv,
                                             unsigned* __restrict__ out, int mode,
                                             const int* __restrict__ col) {
    int lane = threadIdx.x & 63;
    int node = blockIdx.x * 4 + (threadIdx.x >> 6);
    int glane = lane & 15, grp = lane >> 4;
    int rs = rsA[node], re = reA[node];
    int deg = re - rs;
    float a[8];
    #pragma unroll
    for (int i = 0; i < 8; ++i) a[i] = 0.f;
    uint4 selfu = make_uint4(0u, 0u, 0u, 0u);
    if (mode == 0) selfu = xs[(size_t)node * 16 + glane];

    int efull = rs + (deg & ~15);
    for (int base = rs; base < efull; base += 16) {
        int j0 = col[base + grp * 4 + 0];
        int j1 = col[base + grp * 4 + 1];
        int j2 = col[base + grp * 4 + 2];
        int j3 = col[base + grp * 4 + 3];
        uint4 u0 = xs[(size_t)j0 * 16 + glane];
        uint4 u1 = xs[(size_t)j1 * 16 + glane];
        uint4 u2 = xs[(size_t)j2 * 16 + glane];
        uint4 u3 = xs[(size_t)j3 * 16 + glane];
        a[0] += bflo(u0.x) + bflo(u1.x) + bflo(u2.x) + bflo(u3.x);
        a[1] += bfhi(u0.x) + bfhi(u1.x) + bfhi(u2.x) + bfhi(u3.x);
        a[2] += bflo(u0.y) + bflo(u1.y) + bflo(u2.y) + bflo(u3.y);
        a[3] += bfhi(u0.y) + bfhi(u1.y) + bfhi(u2.y) + bfhi(u3.y);
        a[4] += bflo(u0.z) + bflo(u1.z) + bflo(u2.z) + bflo(u3.z);
        a[5] += bfhi(u0.z) + bfhi(u1.z) + bfhi(u2.z) + bfhi(u3.z);
        a[6] += bflo(u0.w) + bflo(u1.w) + bflo(u2.w) + bflo(u3.w);
        a[7] += bfhi(u0.w) + bfhi(u1.w) + bfhi(u2.w) + bfhi(u3.w);
    }
    if (efull < re) {
        int j[4];
        float w[4];
        #pragma unroll
        for (int k = 0; k < 4; ++k) {
            int ee = efull + grp * 4 + k;
            bool v = ee < re;
            j[k] = col[v ? ee : re - 1];
            w[k] = v ? 1.f : 0.f;
        }
        uint4 u0 = xs[(size_t)j[0] * 16 + glane];
        uint4 u1 = xs[(size_t)j[1] * 16 + glane];
        uint4 u2 = xs[(size_t)j[2] * 16 + glane];
        uint4 u3 = xs[(size_t)j[3] * 16 + glane];
        a[0] += w[0] * bflo(u0.x) + w[1] * bflo(u1.x) + w[2] * bflo(u2.x) + w[3] * bflo(u3.x);
        a[1] += w[0] * bfhi(u0.x) + w[1] * bfhi(u1.x) + w[2] * bfhi(u2.x) + w[3] * bfhi(u3.x);
        a[2] += w[0] * bflo(u0.y) + w[1] * bflo(u1.y) + w[2] * bflo(u2.y) + w[3] * bflo(u3.y);
        a[3] += w[0] * bfhi(u0.y) + w[1] * bfhi(u1.y) + w[2] * bfhi(u2.y) + w[3] * bfhi(u3.y);
        a[4] += w[0] * bflo(u0.z) + w[1] * bflo(u1.z) + w[2] * bflo(u2.z) + w[3] * bflo(u3.z);
        a[5] += w[0] * bfhi(u0.z) + w[1] * bfhi(u1.z) + w[2] * bfhi(u2.z) + w[3] * bfhi(u3.z);
        a[6] += w[0] * bflo(u0.w) + w[1] * bflo(u1.w) + w[2] * bflo(u2.w) + w[3] * bflo(u3.w);
        a[7] += w[0] * bfhi(u0.w) + w[1] * bfhi(u1.w) + w[2] * bfhi(u2.w) + w[3] * bfhi(u3.w);
    }
    #pragma unroll
    for (int i = 0; i < 8; ++i) {
        float v = a[i];
        v += __shfl_xor(v, 16, 64);
        v += __shfl_xor(v, 32, 64);
        a[i] = v;
    }
    if (mode == 0) {
        float di = dinv[node];
        a[0] = di * (a[0] + bflo(selfu.x)); a[1] = di * (a[1] + bfhi(selfu.x));
        a[2] = di * (a[2] + bflo(selfu.y)); a[3] = di * (a[3] + bfhi(selfu.y));
        a[4] = di * (a[4] + bflo(selfu.z)); a[5] = di * (a[5] + bfhi(selfu.z));
        a[6] = di * (a[6] + bflo(selfu.w)); a[7] = di * (a[7] + bfhi(selfu.w));
    } else {
        float s = 1.0f / fmaxf((float)deg, 1.0f);
        #pragma unroll
        for (int i = 0; i < 8; ++i) a[i] *= s;
    }
    if (grp == 0) {
        uint4 o;
        o.x = pk(a[0], a[1]); o.y = pk(a[2], a[3]);
        o.z = pk(a[4], a[5]); o.w = pk(a[6], a[7]);
        *(uint4*)(out + (size_t)node * 64 + glane * 4) = o;
    }
}

// ---------------- MFMA GEMM ----------------
template <int DUAL>
__global__ __launch_bounds__(256) void k_gemm(const unsigned short* A0,
                                              const void* __restrict__ W0,
                                              const unsigned short* __restrict__ A1,
                                              const void* __restrict__ W1,
                                              const void* __restrict__ bias,
                                              unsigned short* out,
                                              const int* __restrict__ flags) {
    __shared__ __align__(16) unsigned short As[64][136];
    __shared__ __align__(16) unsigned short Ws[128][136];
    int f32 = flags[0];
    int tid = threadIdx.x;
    int lane = tid & 63;
    int rowbase = blockIdx.x * 64;
    int lr = lane & 15, q = lane >> 4;
    int m0 = (tid >> 6) * 16;

    f4v acc[8];
    #pragma unroll
    for (int t = 0; t < 8; ++t) acc[t] = (f4v){0.f, 0.f, 0.f, 0.f};

    #pragma unroll
    for (int p = 0; p < (DUAL ? 2 : 1); ++p) {
        const unsigned short* Ap = p ? A1 : A0;
        const void* Wp = p ? W1 : W0;
        if (p) __syncthreads();
        #pragma unroll
        for (int it = 0; it < 4; ++it) {
            int chunk = tid + it * 256;
            int r = chunk >> 4, c8 = (chunk & 15) * 8;
            int grow = rowbase + r;
            uint4 v = make_uint4(0u, 0u, 0u, 0u);
            if (grow < N_NODES) v = *(const uint4*)(Ap + (size_t)grow * 128 + c8);
            *(uint4*)&As[r][c8] = v;
        }
        if (!f32) {
            const unsigned short* Wf = (const unsigned short*)Wp;
            #pragma unroll
            for (int it = 0; it < 8; ++it) {
                int chunk = tid + it * 256;
                int r = chunk >> 4, c8 = (chunk & 15) * 8;
                *(uint4*)&Ws[r][c8] = *(const uint4*)(Wf + r * 128 + c8);
            }
        } else {
            const float* Wf = (const float*)Wp;
            #pragma unroll
            for (int it = 0; it < 16; ++it) {
                int chunk = tid + it * 256;
                int r = chunk >> 5, c4 = (chunk & 31) * 4;
                float4 v = *(const float4*)(Wf + r * 128 + c4);
                unsigned lo = (unsigned)f2bf(v.x) | ((unsigned)f2bf(v.y) << 16);
                unsigned hi = (unsigned)f2bf(v.z) | ((unsigned)f2bf(v.w) << 16);
                *(uint2*)&Ws[r][c4] = make_uint2(lo, hi);
            }
        }
        __syncthreads();
        #pragma unroll
        for (int k = 0; k < 4; ++k) {
            s8v a = *(const s8v*)&As[m0 + lr][k * 32 + q * 8];
            #pragma unroll
            for (int t = 0; t < 8; ++t) {
                s8v b = *(const s8v*)&Ws[t * 16 + lr][k * 32 + q * 8];
                acc[t] = __builtin_amdgcn_mfma_f32_16x16x32_bf16(a, b, acc[t], 0, 0, 0);
            }
        }
    }
    #pragma unroll
    for (int t = 0; t < 8; ++t) {
        int o = t * 16 + lr;
        float bv = ldv(bias, o, f32);
        #pragma unroll
        for (int j = 0; j < 4; ++j) {
            int m = rowbase + m0 + q * 4 + j;
            if (m < N_NODES) out[(size_t)m * 128 + o] = f2bf(acc[t][j] + bv);
        }
    }
}

// ---------------- global mean pool, atomic-free, 512 blocks ----------------
__global__ __launch_bounds__(256) void k_pool2(const unsigned* __restrict__ h,
                                               const int* __restrict__ gstart,
                                               float* __restrict__ ppool) {
    __shared__ float part[4][128];
    int g = blockIdx.x / PSPLIT, sl = blockIdx.x % PSPLIT;
    int wave = threadIdx.x >> 6, lane = threadIdx.x & 63;
    int s0 = gstart[g], s1 = gstart[g + 1];
    int n = s1 - s0;
    int chunk = (n + PSPLIT - 1) / PSPLIT;
    int r0 = s0 + sl * chunk;
    int r1 = min(r0 + chunk, s1);
    float a0 = 0.f, a1 = 0.f;
    for (int r = r0 + wave; r < r1; r += 4) {
        unsigned u = h[(size_t)r * 64 + lane];
        a0 += bflo(u);
        a1 += bfhi(u);
    }
    part[wave][2 * lane] = a0;
    part[wave][2 * lane + 1] = a1;
    __syncthreads();
    int t = threadIdx.x;
    if (t < 128) {
        float s = part[0][t] + part[1][t] + part[2][t] + part[3][t];
        ppool[(size_t)blockIdx.x * 128 + t] = s;
    }
}

// ---------------- classifier weight conversion ----------------
__global__ void k_cvt_w(const void* w0, const void* w1, const void* w2, const void* w3,
                        float* __restrict__ wbuf, const int* __restrict__ flags) {
    int f = flags[0];
    int i = blockIdx.x * 256 + threadIdx.x;
    if (i < 25600) wbuf[i] = ldv(w0, i, f);
    else if (i < 45600) wbuf[i] = ldv(w1, i - 25600, f);
    else if (i < 50600) wbuf[i] = ldv(w2, i - 45600, f);
    else if (i < 51100) wbuf[i] = ldv(w3, i - 50600, f);
}

// ---------------- classifier layers ----------------
__global__ __launch_bounds__(256) void k_clf0(const float* __restrict__ ppool,
                                              const int* __restrict__ gstart,
                                              const float* __restrict__ wbuf,
                                              const float* __restrict__ pbuf,
                                              float* __restrict__ h1) {
    __shared__ float g[128];
    int b = blockIdx.x, t = threadIdx.x;
    if (t < 128) {
        float s = 0.f;
        #pragma unroll
        for (int k = 0; k < PSPLIT; ++k) s += ppool[(size_t)(b * PSPLIT + k) * 128 + t];
        int cnt = gstart[b + 1] - gstart[b];
        g[t] = s / fmaxf((float)cnt, 1.0f);
    }
    __syncthreads();
    if (t < 200) {
        const float4* wr = (const float4*)(wbuf + t * 128);
        float s = 0.f;
        #pragma unroll
        for (int k = 0; k < 32; ++k) {
            float4 v = wr[k];
            s += v.x * g[4 * k] + v.y * g[4 * k + 1] + v.z * g[4 * k + 2] + v.w * g[4 * k + 3];
        }
        h1[b * 200 + t] = tanhf(s * pbuf[t] + pbuf[200 + t]);
    }
}

__global__ __launch_bounds__(128) void k_clf1(const float* __restrict__ h1,
                                              const float* __restrict__ wbuf,
                                              const float* __restrict__ pbuf,
                                              float* __restrict__ h2) {
    __shared__ float g[200];
    int b = blockIdx.x, t = threadIdx.x;
    for (int i = t; i < 200; i += 128) g[i] = h1[b * 200 + i];
    __syncthreads();
    if (t < 100) {
        const float4* wr = (const float4*)(wbuf + 25600 + t * 200);
        float s = 0.f;
        #pragma unroll
        for (int k = 0; k < 50; ++k) {
            float4 v = wr[k];
            s += v.x * g[4 * k] + v.y * g[4 * k + 1] + v.z * g[4 * k + 2] + v.w * g[4 * k + 3];
        }
        h2[b * 100 + t] = tanhf(s * pbuf[400 + t] + pbuf[500 + t]);
    }
}

__global__ __launch_bounds__(128) void k_clf2(const float* __restrict__ h2,
                                              const float* __restrict__ wbuf,
                                              const float* __restrict__ pbuf,
                                              float* __restrict__ h3) {
    __shared__ float g[100];
    int b = blockIdx.x, t = threadIdx.x;
    if (t < 100) g[t] = h2[b * 100 + t];
    __syncthreads();
    if (t < 50) {
        const float4* wr = (const float4*)(wbuf + 45600 + t * 100);
        float s = 0.f;
        #pragma unroll
        for (int k = 0; k < 25; ++k) {
            float4 v = wr[k];
            s += v.x * g[4 * k] + v.y * g[4 * k + 1] + v.z * g[4 * k + 2] + v.w * g[4 * k + 3];
        }
        h3[b * 50 + t] = tanhf(s * pbuf[600 + t] + pbuf[650 + t]);
    }
}

__global__ __launch_bounds__(64) void k_clf3(const float* __restrict__ h3,
                                             const float* __restrict__ wbuf,
                                             const float* __restrict__ pbuf,
                                             void* outv, const int* __restrict__ flags) {
    int b = threadIdx.x;
    int f = flags[0];
    const float* h = h3 + b * 50;
    float lg[10];
    float mx = -1e30f;
    #pragma unroll
    for (int c = 0; c < 10; ++c) {
        const float* wr = wbuf + 50600 + c * 50;
        float s = 0.f;
        for (int k = 0; k < 50; ++k) s += wr[k] * h[k];
        s += pbuf[700 + c];
        lg[c] = s;
        mx = fmaxf(mx, s);
    }
    float sum = 0.f;
    #pragma unroll
    for (int c = 0; c < 10; ++c) {
        lg[c] = __expf(lg[c] - mx);
        sum += lg[c];
    }
    float inv = 1.0f / sum;
    #pragma unroll
    for (int c = 0; c < 10; ++c) {
        float v = lg[c] * inv;
        if (f) ((float*)outv)[b * 10 + c] = v;
        else ((unsigned short*)outv)[b * 10 + c] = f2bf(v);
    }
}

extern "C" void kernel_launch(void* const* d_in, const int* in_sizes, int n_in,
                              void* d_out, int out_size, void* d_ws, size_t ws_size,
                              hipStream_t stream) {
    const unsigned short* x16 = (const unsigned short*)d_in[0];
    const int* ei = (const int*)d_in[1];
    const int* batch = (const int*)d_in[2];

    char* ws = (char*)d_ws;
    size_t off = 0;
    auto alloc = [&](size_t bytes) {
        size_t r = off;
        off = (off + bytes + 255) & ~(size_t)255;
        return r;
    };
    int* flags = (int*)(ws + alloc(256));
    int* rsA = (int*)(ws + alloc((size_t)N_NODES * 4));
    int* reA = (int*)(ws + alloc((size_t)N_NODES * 4));
    int* colidx = (int*)(ws + alloc((size_t)NBIN * CAPB * 4));
    float* dinv = (float*)(ws + alloc((size_t)N_NODES * 4));
    int* binCur = (int*)(ws + alloc(NBIN * 4));
    int* gstart = (int*)(ws + alloc((NGRAPH + 1) * 4));
    float* pbuf = (float*)(ws + alloc(710 * 4));
    float* ppool = (float*)(ws + alloc((size_t)NGRAPH * PSPLIT * 128 * 4));
    float* wbuf = (float*)(ws + alloc(51100 * 4));
    float* h1 = (float*)(ws + alloc(64 * 200 * 4));
    float* h2 = (float*)(ws + alloc(64 * 100 * 4));
    float* h3 = (float*)(ws + alloc(64 * 50 * 4));
    unsigned short* bufA = (unsigned short*)(ws + alloc((size_t)N_NODES * 128 * 2));
    unsigned short* bufB = (unsigned short*)(ws + alloc((size_t)N_NODES * 128 * 2));
    unsigned* staging = (unsigned*)bufA;  // 9.6 MB < 25.6 MB; consumed before k_agg writes bufA

    k_setup<<<1, 256, 0, stream>>>(x16, ei, batch, flags, binCur, gstart, pbuf,
                                   d_in[12], d_in[19], d_in[20],
                                   d_in[14], d_in[21], d_in[22],
                                   d_in[16], d_in[23], d_in[24], d_in[18]);
    k_cvt_w<<<200, 256, 0, stream>>>(d_in[11], d_in[13], d_in[15], d_in[17], wbuf, flags);

    // padded-bin CSR build + fused prescale (y = dinv*x -> bufB)
    k_binfill<<<NBLK, 256, 0, stream>>>(ei, binCur, staging, flags);
    k_csr<<<NBIN, 256, 0, stream>>>(staging, binCur, rsA, reA, dinv, colidx,
                                    (const void*)x16, (unsigned*)bufB, flags);

    // GCN: agg-sum(y)+self, scale dinv -> bufA; gemm in-place
    k_agg<<<N_NODES / 4, 256, 0, stream>>>((const uint4*)bufB, rsA, reA, dinv,
                                           (unsigned*)bufA, 0, colidx);
    k_gemm<0><<<(N_NODES + 63) / 64, 256, 0, stream>>>(bufA, d_in[3], nullptr, nullptr, d_in[4],
                                                       bufA, flags);
    // SAGE1
    k_agg<<<N_NODES / 4, 256, 0, stream>>>((const uint4*)bufA, rsA, reA, dinv,
                                           (unsigned*)bufB, 1, colidx);
    k_gemm<1><<<(N_NODES + 63) / 64, 256, 0, stream>>>(bufB, d_in[5], bufA, d_in[7], d_in[6],
                                                       bufB, flags);
    // SAGE2
    k_agg<<<N_NODES / 4, 256, 0, stream>>>((const uint4*)bufB, rsA, reA, dinv,
                                           (unsigned*)bufA, 1, colidx);
    k_gemm<1><<<(N_NODES + 63) / 64, 256, 0, stream>>>(bufA, d_in[8], bufB, d_in[10], d_in[9],
                                                       bufA, flags);
    // pool + classifier (512-block parallel pool, small per-graph layers)
    k_pool2<<<NGRAPH * PSPLIT, 256, 0, stream>>>((const unsigned*)bufA, gstart, ppool);
    k_clf0<<<NGRAPH, 256, 0, stream>>>(ppool, gstart, wbuf, pbuf, h1);
    k_clf1<<<NGRAPH, 128, 0, stream>>>(h1, wbuf, pbuf, h2);
    k_clf2<<<NGRAPH, 128, 0, stream>>>(h2, wbuf, pbuf, h3);
    k_clf3<<<1, 64, 0, stream>>>(h3, wbuf, pbuf, d_out, flags);
}

// Round 13
// 516.098 us; speedup vs baseline: 1.1023x; 1.0582x over previous
//
#include <hip/hip_runtime.h>

#define N_NODES 100000
#define N_EDGES 1600000
#define NGRAPH 64
#define NBIN 391        // ceil(100000/256) bins of 256 nodes (dst>>8)
#define EPB 6400        // edges per binning block
#define NBLK 250        // 250*6400 = 1.6M
#define CAPB 6144       // padded per-bin capacity (avg 4092, +32 sigma)
#define CAP 8192        // LDS capacity in k_csr
#define PSPLIT 8        // pool slices per graph

typedef short s8v __attribute__((ext_vector_type(8)));
typedef float f4v __attribute__((ext_vector_type(4)));

__device__ __forceinline__ float bflo(unsigned u) { return __uint_as_float(u << 16); }
__device__ __forceinline__ float bfhi(unsigned u) { return __uint_as_float(u & 0xffff0000u); }
__device__ __forceinline__ unsigned short f2bf(float f) {
    unsigned u = __float_as_uint(f);
    u += 0x7fffu + ((u >> 16) & 1u);
    return (unsigned short)(u >> 16);
}
__device__ __forceinline__ float bf2f(unsigned short h) { return __uint_as_float(((unsigned)h) << 16); }
__device__ __forceinline__ unsigned pk(float lo, float hi) {
    return (unsigned)f2bf(lo) | ((unsigned)f2bf(hi) << 16);
}
__device__ __forceinline__ float ldv(const void* p, int i, int f32) {
    return f32 ? ((const float*)p)[i] : bf2f(((const unsigned short*)p)[i]);
}

// ---------------- setup: detect + bininit + graph bounds + classifier params ------
__global__ __launch_bounds__(256) void k_setup(const unsigned short* __restrict__ x,
                                               const int* __restrict__ ei,
                                               const int* __restrict__ batch,
                                               int* __restrict__ flags,
                                               int* __restrict__ binCur,
                                               int* __restrict__ gstart,
                                               float* __restrict__ pbuf,
                                               const void* b0, const void* bn0g, const void* bn0b,
                                               const void* b1, const void* bn1g, const void* bn1b,
                                               const void* b2, const void* bn2g, const void* bn2b,
                                               const void* b3) {
    __shared__ int cnt[3];
    int tid = threadIdx.x;
    if (tid < 3) cnt[tid] = 0;
    __syncthreads();
    unsigned short h = x[tid * 37];
    int e = (h >> 7) & 0xFF;
    if (e >= 100 && e <= 150) atomicAdd(&cnt[0], 1);
    if (ei[2 * (tid * 5000) + 1] == 0) atomicAdd(&cnt[1], 1);
    if (batch[2 * (tid * 193) + 1] == 0) atomicAdd(&cnt[2], 1);
    __syncthreads();
    int f = (cnt[0] == 256) ? 0 : 1;
    int b64 = (cnt[2] == 256) ? 1 : 0;
    if (tid == 0) {
        flags[0] = f;
        flags[1] = (cnt[1] == 256) ? 1 : 0;
        flags[2] = b64;
    }
    for (int i = tid; i < NBIN; i += 256) binCur[i] = i * CAPB;
    if (tid <= NGRAPH) {
        int g = tid, lo = 0, hi = N_NODES;
        while (lo < hi) {
            int mid = (lo + hi) >> 1;
            int v = b64 ? batch[2 * mid] : batch[mid];
            if (v < g) lo = mid + 1;
            else hi = mid;
        }
        gstart[g] = lo;
    }
    const float invs = rsqrtf(1.0f + 1e-5f);
    if (tid < 200) {
        float a = ldv(bn0g, tid, f) * invs;
        pbuf[tid] = a;
        pbuf[200 + tid] = ldv(b0, tid, f) * a + ldv(bn0b, tid, f);
    }
    if (tid < 100) {
        float a = ldv(bn1g, tid, f) * invs;
        pbuf[400 + tid] = a;
        pbuf[500 + tid] = ldv(b1, tid, f) * a + ldv(bn1b, tid, f);
    }
    if (tid < 50) {
        float a = ldv(bn2g, tid, f) * invs;
        pbuf[600 + tid] = a;
        pbuf[650 + tid] = ldv(b2, tid, f) * a + ldv(bn2b, tid, f);
    }
    if (tid < 10) pbuf[700 + tid] = ldv(b3, tid, f);
}

// ---------------- CSR build: padded bins ----------------
__global__ __launch_bounds__(256) void k_binfill(const int* __restrict__ ei,
                                                 int* __restrict__ binCur,
                                                 unsigned* __restrict__ staging,
                                                 const int* __restrict__ flags) {
    __shared__ int cnt[NBIN];
    __shared__ int lofs[NBIN];
    __shared__ int curL[NBIN];
    __shared__ int basg[NBIN];
    __shared__ int sA[512], sB[512];
    __shared__ unsigned ebuf[EPB];
    int tid = threadIdx.x;
    int i64 = flags[1];
    int base = blockIdx.x * EPB;
    for (int i = tid; i < NBIN; i += 256) cnt[i] = 0;
    __syncthreads();
    for (int k = 0; k < EPB / 256; ++k) {
        int e = base + k * 256 + tid;
        int d = i64 ? ei[2 * (N_EDGES + e)] : ei[N_EDGES + e];
        if ((unsigned)d < N_NODES) atomicAdd(&cnt[d >> 8], 1);
    }
    __syncthreads();
    for (int k = tid; k < 512; k += 256) sA[k] = (k < NBIN) ? cnt[k] : 0;
    __syncthreads();
    int* src = sA;
    int* dst = sB;
    for (int off = 1; off < 512; off <<= 1) {
        for (int k = tid; k < 512; k += 256)
            dst[k] = src[k] + ((k >= off) ? src[k - off] : 0);
        __syncthreads();
        int* t = src; src = dst; dst = t;
    }
    for (int i = tid; i < NBIN; i += 256) {
        int excl = src[i] - cnt[i];
        lofs[i] = excl;
        curL[i] = excl;
        basg[i] = cnt[i] ? atomicAdd(&binCur[i], cnt[i]) : 0;
    }
    __syncthreads();
    for (int k = 0; k < EPB / 256; ++k) {
        int e = base + k * 256 + tid;
        int s = i64 ? ei[2 * e] : ei[e];
        int d = i64 ? ei[2 * (N_EDGES + e)] : ei[N_EDGES + e];
        if ((unsigned)d < N_NODES) {
            s = min(max(s, 0), N_NODES - 1);
            int p = atomicAdd(&curL[d >> 8], 1);
            ebuf[p] = ((unsigned)(d & 255) << 20) | (unsigned)s;
        }
    }
    __syncthreads();
    int wid = tid >> 6, lane = tid & 63;
    for (int b = wid; b < NBIN; b += 4) {
        int n = cnt[b], lo = lofs[b], go = basg[b];
        int cap = (b + 1) * CAPB;
        for (int l = lane; l < n; l += 64)
            if (go + l < cap) staging[go + l] = ebuf[lo + l];
    }
}

// per-bin sub-CSR entirely in LDS -> row start/end + dinv + colidx (padded layout)
__global__ __launch_bounds__(256) void k_csr(const unsigned* __restrict__ staging,
                                             const int* __restrict__ binCur,
                                             int* __restrict__ rsA, int* __restrict__ reA,
                                             float* __restrict__ dinv,
                                             int* __restrict__ colidx) {
    __shared__ int deg[256];
    __shared__ int s[256];
    __shared__ int cur[256];
    __shared__ unsigned ebuf[CAP];
    __shared__ int colbuf[CAP];
    int b = blockIdx.x, tid = threadIdx.x;
    int n0 = b << 8;
    int nend = min(256, N_NODES - n0);
    int runStart = b * CAPB;
    int runLen = min(binCur[b] - runStart, CAPB);
    deg[tid] = 0;
    __syncthreads();
    for (int i = tid; i < runLen; i += 256) {
        unsigned e = staging[runStart + i];
        ebuf[i] = e;
        atomicAdd(&deg[e >> 20], 1);
    }
    __syncthreads();
    int myDeg = deg[tid];
    s[tid] = myDeg;
    __syncthreads();
    for (int off = 1; off < 256; off <<= 1) {
        int x2 = (tid >= off) ? s[tid - off] : 0;
        __syncthreads();
        s[tid] += x2;
        __syncthreads();
    }
    int incl = s[tid];
    if (tid < nend) {
        rsA[n0 + tid] = runStart + incl - myDeg;
        reA[n0 + tid] = runStart + incl;
        dinv[n0 + tid] = rsqrtf((float)myDeg + 1.0f);
    }
    cur[tid] = incl - myDeg;
    __syncthreads();
    for (int i = tid; i < runLen; i += 256) {
        unsigned e = ebuf[i];
        int p = atomicAdd(&cur[e >> 20], 1);
        colbuf[p] = (int)(e & 0xFFFFF);
    }
    __syncthreads();
    for (int i = tid; i < runLen; i += 256) colidx[runStart + i] = colbuf[i];
}

// ---------------- prescale: y[i] = dinv[i] * x[i] (dedicated, full occupancy) -----
__global__ __launch_bounds__(256) void k_prescale(const void* __restrict__ src,
                                                  const float* __restrict__ dinv,
                                                  unsigned* __restrict__ out,
                                                  const int* __restrict__ flags) {
    int id = blockIdx.x * 256 + threadIdx.x;
    int node = id >> 6;
    float di = dinv[node];
    float lo, hi;
    if (flags[0]) {
        float2 u = ((const float2*)src)[id];
        lo = u.x; hi = u.y;
    } else {
        unsigned u = ((const unsigned*)src)[id];
        lo = bflo(u); hi = bfhi(u);
    }
    out[id] = pk(di * lo, di * hi);
}

// ---------------- unified aggregation: gather-sum over bf16 rows ----------------
__global__ __launch_bounds__(256) void k_agg(const uint4* __restrict__ xs,
                                             const int* __restrict__ rsA,
                                             const int* __restrict__ reA,
                                             const float* __restrict__ dinv,
                                             unsigned* __restrict__ out, int mode,
                                             const int* __restrict__ col) {
    int lane = threadIdx.x & 63;
    int node = blockIdx.x * 4 + (threadIdx.x >> 6);
    int glane = lane & 15, grp = lane >> 4;
    int rs = rsA[node], re = reA[node];
    int deg = re - rs;
    float a[8];
    #pragma unroll
    for (int i = 0; i < 8; ++i) a[i] = 0.f;
    uint4 selfu = make_uint4(0u, 0u, 0u, 0u);
    if (mode == 0) selfu = xs[(size_t)node * 16 + glane];

    int efull = rs + (deg & ~15);
    for (int base = rs; base < efull; base += 16) {
        int j0 = col[base + grp * 4 + 0];
        int j1 = col[base + grp * 4 + 1];
        int j2 = col[base + grp * 4 + 2];
        int j3 = col[base + grp * 4 + 3];
        uint4 u0 = xs[(size_t)j0 * 16 + glane];
        uint4 u1 = xs[(size_t)j1 * 16 + glane];
        uint4 u2 = xs[(size_t)j2 * 16 + glane];
        uint4 u3 = xs[(size_t)j3 * 16 + glane];
        a[0] += bflo(u0.x) + bflo(u1.x) + bflo(u2.x) + bflo(u3.x);
        a[1] += bfhi(u0.x) + bfhi(u1.x) + bfhi(u2.x) + bfhi(u3.x);
        a[2] += bflo(u0.y) + bflo(u1.y) + bflo(u2.y) + bflo(u3.y);
        a[3] += bfhi(u0.y) + bfhi(u1.y) + bfhi(u2.y) + bfhi(u3.y);
        a[4] += bflo(u0.z) + bflo(u1.z) + bflo(u2.z) + bflo(u3.z);
        a[5] += bfhi(u0.z) + bfhi(u1.z) + bfhi(u2.z) + bfhi(u3.z);
        a[6] += bflo(u0.w) + bflo(u1.w) + bflo(u2.w) + bflo(u3.w);
        a[7] += bfhi(u0.w) + bfhi(u1.w) + bfhi(u2.w) + bfhi(u3.w);
    }
    if (efull < re) {
        int j[4];
        float w[4];
        #pragma unroll
        for (int k = 0; k < 4; ++k) {
            int ee = efull + grp * 4 + k;
            bool v = ee < re;
            j[k] = col[v ? ee : re - 1];
            w[k] = v ? 1.f : 0.f;
        }
        uint4 u0 = xs[(size_t)j[0] * 16 + glane];
        uint4 u1 = xs[(size_t)j[1] * 16 + glane];
        uint4 u2 = xs[(size_t)j[2] * 16 + glane];
        uint4 u3 = xs[(size_t)j[3] * 16 + glane];
        a[0] += w[0] * bflo(u0.x) + w[1] * bflo(u1.x) + w[2] * bflo(u2.x) + w[3] * bflo(u3.x);
        a[1] += w[0] * bfhi(u0.x) + w[1] * bfhi(u1.x) + w[2] * bfhi(u2.x) + w[3] * bfhi(u3.x);
        a[2] += w[0] * bflo(u0.y) + w[1] * bflo(u1.y) + w[2] * bflo(u2.y) + w[3] * bflo(u3.y);
        a[3] += w[0] * bfhi(u0.y) + w[1] * bfhi(u1.y) + w[2] * bfhi(u2.y) + w[3] * bfhi(u3.y);
        a[4] += w[0] * bflo(u0.z) + w[1] * bflo(u1.z) + w[2] * bflo(u2.z) + w[3] * bflo(u3.z);
        a[5] += w[0] * bfhi(u0.z) + w[1] * bfhi(u1.z) + w[2] * bfhi(u2.z) + w[3] * bfhi(u3.z);
        a[6] += w[0] * bflo(u0.w) + w[1] * bflo(u1.w) + w[2] * bflo(u2.w) + w[3] * bflo(u3.w);
        a[7] += w[0] * bfhi(u0.w) + w[1] * bfhi(u1.w) + w[2] * bfhi(u2.w) + w[3] * bfhi(u3.w);
    }
    #pragma unroll
    for (int i = 0; i < 8; ++i) {
        float v = a[i];
        v += __shfl_xor(v, 16, 64);
        v += __shfl_xor(v, 32, 64);
        a[i] = v;
    }
    if (mode == 0) {
        float di = dinv[node];
        a[0] = di * (a[0] + bflo(selfu.x)); a[1] = di * (a[1] + bfhi(selfu.x));
        a[2] = di * (a[2] + bflo(selfu.y)); a[3] = di * (a[3] + bfhi(selfu.y));
        a[4] = di * (a[4] + bflo(selfu.z)); a[5] = di * (a[5] + bfhi(selfu.z));
        a[6] = di * (a[6] + bflo(selfu.w)); a[7] = di * (a[7] + bfhi(selfu.w));
    } else {
        float s = 1.0f / fmaxf((float)deg, 1.0f);
        #pragma unroll
        for (int i = 0; i < 8; ++i) a[i] *= s;
    }
    if (grp == 0) {
        uint4 o;
        o.x = pk(a[0], a[1]); o.y = pk(a[2], a[3]);
        o.z = pk(a[4], a[5]); o.w = pk(a[6], a[7]);
        *(uint4*)(out + (size_t)node * 64 + glane * 4) = o;
    }
}

// ---------------- MFMA GEMM ----------------
template <int DUAL>
__global__ __launch_bounds__(256) void k_gemm(const unsigned short* A0,
                                              const void* __restrict__ W0,
                                              const unsigned short* __restrict__ A1,
                                              const void* __restrict__ W1,
                                              const void* __restrict__ bias,
                                              unsigned short* out,
                                              const int* __restrict__ flags) {
    __shared__ __align__(16) unsigned short As[64][136];
    __shared__ __align__(16) unsigned short Ws[128][136];
    int f32 = flags[0];
    int tid = threadIdx.x;
    int lane = tid & 63;
    int rowbase = blockIdx.x * 64;
    int lr = lane & 15, q = lane >> 4;
    int m0 = (tid >> 6) * 16;

    f4v acc[8];
    #pragma unroll
    for (int t = 0; t < 8; ++t) acc[t] = (f4v){0.f, 0.f, 0.f, 0.f};

    #pragma unroll
    for (int p = 0; p < (DUAL ? 2 : 1); ++p) {
        const unsigned short* Ap = p ? A1 : A0;
        const void* Wp = p ? W1 : W0;
        if (p) __syncthreads();
        #pragma unroll
        for (int it = 0; it < 4; ++it) {
            int chunk = tid + it * 256;
            int r = chunk >> 4, c8 = (chunk & 15) * 8;
            int grow = rowbase + r;
            uint4 v = make_uint4(0u, 0u, 0u, 0u);
            if (grow < N_NODES) v = *(const uint4*)(Ap + (size_t)grow * 128 + c8);
            *(uint4*)&As[r][c8] = v;
        }
        if (!f32) {
            const unsigned short* Wf = (const unsigned short*)Wp;
            #pragma unroll
            for (int it = 0; it < 8; ++it) {
                int chunk = tid + it * 256;
                int r = chunk >> 4, c8 = (chunk & 15) * 8;
                *(uint4*)&Ws[r][c8] = *(const uint4*)(Wf + r * 128 + c8);
            }
        } else {
            const float* Wf = (const float*)Wp;
            #pragma unroll
            for (int it = 0; it < 16; ++it) {
                int chunk = tid + it * 256;
                int r = chunk >> 5, c4 = (chunk & 31) * 4;
                float4 v = *(const float4*)(Wf + r * 128 + c4);
                unsigned lo = (unsigned)f2bf(v.x) | ((unsigned)f2bf(v.y) << 16);
                unsigned hi = (unsigned)f2bf(v.z) | ((unsigned)f2bf(v.w) << 16);
                *(uint2*)&Ws[r][c4] = make_uint2(lo, hi);
            }
        }
        __syncthreads();
        #pragma unroll
        for (int k = 0; k < 4; ++k) {
            s8v a = *(const s8v*)&As[m0 + lr][k * 32 + q * 8];
            #pragma unroll
            for (int t = 0; t < 8; ++t) {
                s8v b = *(const s8v*)&Ws[t * 16 + lr][k * 32 + q * 8];
                acc[t] = __builtin_amdgcn_mfma_f32_16x16x32_bf16(a, b, acc[t], 0, 0, 0);
            }
        }
    }
    #pragma unroll
    for (int t = 0; t < 8; ++t) {
        int o = t * 16 + lr;
        float bv = ldv(bias, o, f32);
        #pragma unroll
        for (int j = 0; j < 4; ++j) {
            int m = rowbase + m0 + q * 4 + j;
            if (m < N_NODES) out[(size_t)m * 128 + o] = f2bf(acc[t][j] + bv);
        }
    }
}

// ---------------- global mean pool, atomic-free, 512 blocks ----------------
__global__ __launch_bounds__(256) void k_pool2(const unsigned* __restrict__ h,
                                               const int* __restrict__ gstart,
                                               float* __restrict__ ppool) {
    __shared__ float part[4][128];
    int g = blockIdx.x / PSPLIT, sl = blockIdx.x % PSPLIT;
    int wave = threadIdx.x >> 6, lane = threadIdx.x & 63;
    int s0 = gstart[g], s1 = gstart[g + 1];
    int n = s1 - s0;
    int chunk = (n + PSPLIT - 1) / PSPLIT;
    int r0 = s0 + sl * chunk;
    int r1 = min(r0 + chunk, s1);
    float a0 = 0.f, a1 = 0.f;
    for (int r = r0 + wave; r < r1; r += 4) {
        unsigned u = h[(size_t)r * 64 + lane];
        a0 += bflo(u);
        a1 += bfhi(u);
    }
    part[wave][2 * lane] = a0;
    part[wave][2 * lane + 1] = a1;
    __syncthreads();
    int t = threadIdx.x;
    if (t < 128) {
        float s = part[0][t] + part[1][t] + part[2][t] + part[3][t];
        ppool[(size_t)blockIdx.x * 128 + t] = s;
    }
}

// ---------------- classifier weight conversion ----------------
__global__ void k_cvt_w(const void* w0, const void* w1, const void* w2, const void* w3,
                        float* __restrict__ wbuf, const int* __restrict__ flags) {
    int f = flags[0];
    int i = blockIdx.x * 256 + threadIdx.x;
    if (i < 25600) wbuf[i] = ldv(w0, i, f);
    else if (i < 45600) wbuf[i] = ldv(w1, i - 25600, f);
    else if (i < 50600) wbuf[i] = ldv(w2, i - 45600, f);
    else if (i < 51100) wbuf[i] = ldv(w3, i - 50600, f);
}

// ---------------- classifier layers ----------------
__global__ __launch_bounds__(256) void k_clf0(const float* __restrict__ ppool,
                                              const int* __restrict__ gstart,
                                              const float* __restrict__ wbuf,
                                              const float* __restrict__ pbuf,
                                              float* __restrict__ h1) {
    __shared__ float g[128];
    int b = blockIdx.x, t = threadIdx.x;
    if (t < 128) {
        float s = 0.f;
        #pragma unroll
        for (int k = 0; k < PSPLIT; ++k) s += ppool[(size_t)(b * PSPLIT + k) * 128 + t];
        int cnt = gstart[b + 1] - gstart[b];
        g[t] = s / fmaxf((float)cnt, 1.0f);
    }
    __syncthreads();
    if (t < 200) {
        const float4* wr = (const float4*)(wbuf + t * 128);
        float s = 0.f;
        #pragma unroll
        for (int k = 0; k < 32; ++k) {
            float4 v = wr[k];
            s += v.x * g[4 * k] + v.y * g[4 * k + 1] + v.z * g[4 * k + 2] + v.w * g[4 * k + 3];
        }
        h1[b * 200 + t] = tanhf(s * pbuf[t] + pbuf[200 + t]);
    }
}

__global__ __launch_bounds__(128) void k_clf1(const float* __restrict__ h1,
                                              const float* __restrict__ wbuf,
                                              const float* __restrict__ pbuf,
                                              float* __restrict__ h2) {
    __shared__ float g[200];
    int b = blockIdx.x, t = threadIdx.x;
    for (int i = t; i < 200; i += 128) g[i] = h1[b * 200 + i];
    __syncthreads();
    if (t < 100) {
        const float4* wr = (const float4*)(wbuf + 25600 + t * 200);
        float s = 0.f;
        #pragma unroll
        for (int k = 0; k < 50; ++k) {
            float4 v = wr[k];
            s += v.x * g[4 * k] + v.y * g[4 * k + 1] + v.z * g[4 * k + 2] + v.w * g[4 * k + 3];
        }
        h2[b * 100 + t] = tanhf(s * pbuf[400 + t] + pbuf[500 + t]);
    }
}

__global__ __launch_bounds__(128) void k_clf2(const float* __restrict__ h2,
                                              const float* __restrict__ wbuf,
                                              const float* __restrict__ pbuf,
                                              float* __restrict__ h3) {
    __shared__ float g[100];
    int b = blockIdx.x, t = threadIdx.x;
    if (t < 100) g[t] = h2[b * 100 + t];
    __syncthreads();
    if (t < 50) {
        const float4* wr = (const float4*)(wbuf + 45600 + t * 100);
        float s = 0.f;
        #pragma unroll
        for (int k = 0; k < 25; ++k) {
            float4 v = wr[k];
            s += v.x * g[4 * k] + v.y * g[4 * k + 1] + v.z * g[4 * k + 2] + v.w * g[4 * k + 3];
        }
        h3[b * 50 + t] = tanhf(s * pbuf[600 + t] + pbuf[650 + t]);
    }
}

__global__ __launch_bounds__(64) void k_clf3(const float* __restrict__ h3,
                                             const float* __restrict__ wbuf,
                                             const float* __restrict__ pbuf,
                                             void* outv, const int* __restrict__ flags) {
    int b = threadIdx.x;
    int f = flags[0];
    const float* h = h3 + b * 50;
    float lg[10];
    float mx = -1e30f;
    #pragma unroll
    for (int c = 0; c < 10; ++c) {
        const float* wr = wbuf + 50600 + c * 50;
        float s = 0.f;
        for (int k = 0; k < 50; ++k) s += wr[k] * h[k];
        s += pbuf[700 + c];
        lg[c] = s;
        mx = fmaxf(mx, s);
    }
    float sum = 0.f;
    #pragma unroll
    for (int c = 0; c < 10; ++c) {
        lg[c] = __expf(lg[c] - mx);
        sum += lg[c];
    }
    float inv = 1.0f / sum;
    #pragma unroll
    for (int c = 0; c < 10; ++c) {
        float v = lg[c] * inv;
        if (f) ((float*)outv)[b * 10 + c] = v;
        else ((unsigned short*)outv)[b * 10 + c] = f2bf(v);
    }
}

extern "C" void kernel_launch(void* const* d_in, const int* in_sizes, int n_in,
                              void* d_out, int out_size, void* d_ws, size_t ws_size,
                              hipStream_t stream) {
    const unsigned short* x16 = (const unsigned short*)d_in[0];
    const int* ei = (const int*)d_in[1];
    const int* batch = (const int*)d_in[2];

    char* ws = (char*)d_ws;
    size_t off = 0;
    auto alloc = [&](size_t bytes) {
        size_t r = off;
        off = (off + bytes + 255) & ~(size_t)255;
        return r;
    };
    int* flags = (int*)(ws + alloc(256));
    int* rsA = (int*)(ws + alloc((size_t)N_NODES * 4));
    int* reA = (int*)(ws + alloc((size_t)N_NODES * 4));
    int* colidx = (int*)(ws + alloc((size_t)NBIN * CAPB * 4));
    float* dinv = (float*)(ws + alloc((size_t)N_NODES * 4));
    int* binCur = (int*)(ws + alloc(NBIN * 4));
    int* gstart = (int*)(ws + alloc((NGRAPH + 1) * 4));
    float* pbuf = (float*)(ws + alloc(710 * 4));
    float* ppool = (float*)(ws + alloc((size_t)NGRAPH * PSPLIT * 128 * 4));
    float* wbuf = (float*)(ws + alloc(51100 * 4));
    float* h1 = (float*)(ws + alloc(64 * 200 * 4));
    float* h2 = (float*)(ws + alloc(64 * 100 * 4));
    float* h3 = (float*)(ws + alloc(64 * 50 * 4));
    unsigned short* bufA = (unsigned short*)(ws + alloc((size_t)N_NODES * 128 * 2));
    unsigned short* bufB = (unsigned short*)(ws + alloc((size_t)N_NODES * 128 * 2));
    unsigned* staging = (unsigned*)bufA;  // 9.6 MB < 25.6 MB; consumed before k_agg writes bufA

    k_setup<<<1, 256, 0, stream>>>(x16, ei, batch, flags, binCur, gstart, pbuf,
                                   d_in[12], d_in[19], d_in[20],
                                   d_in[14], d_in[21], d_in[22],
                                   d_in[16], d_in[23], d_in[24], d_in[18]);
    k_cvt_w<<<200, 256, 0, stream>>>(d_in[11], d_in[13], d_in[15], d_in[17], wbuf, flags);

    // padded-bin CSR build
    k_binfill<<<NBLK, 256, 0, stream>>>(ei, binCur, staging, flags);
    k_csr<<<NBIN, 256, 0, stream>>>(staging, binCur, rsA, reA, dinv, colidx);

    // GCN: y = dinv*x -> bufB (dedicated full-occupancy prescale); agg; gemm in-place
    k_prescale<<<N_NODES * 64 / 256, 256, 0, stream>>>((const void*)x16, dinv,
                                                       (unsigned*)bufB, flags);
    k_agg<<<N_NODES / 4, 256, 0, stream>>>((const uint4*)bufB, rsA, reA, dinv,
                                           (unsigned*)bufA, 0, colidx);
    k_gemm<0><<<(N_NODES + 63) / 64, 256, 0, stream>>>(bufA, d_in[3], nullptr, nullptr, d_in[4],
                                                       bufA, flags);
    // SAGE1
    k_agg<<<N_NODES / 4, 256, 0, stream>>>((const uint4*)bufA, rsA, reA, dinv,
                                           (unsigned*)bufB, 1, colidx);
    k_gemm<1><<<(N_NODES + 63) / 64, 256, 0, stream>>>(bufB, d_in[5], bufA, d_in[7], d_in[6],
                                                       bufB, flags);
    // SAGE2
    k_agg<<<N_NODES / 4, 256, 0, stream>>>((const uint4*)bufB, rsA, reA, dinv,
                                           (unsigned*)bufA, 1, colidx);
    k_gemm<1><<<(N_NODES + 63) / 64, 256, 0, stream>>>(bufA, d_in[8], bufB, d_in[10], d_in[9],
                                                       bufA, flags);
    // pool + classifier
    k_pool2<<<NGRAPH * PSPLIT, 256, 0, stream>>>((const unsigned*)bufA, gstart, ppool);
    k_clf0<<<NGRAPH, 256, 0, stream>>>(ppool, gstart, wbuf, pbuf, h1);
    k_clf1<<<NGRAPH, 128, 0, stream>>>(h1, wbuf, pbuf, h2);
    k_clf2<<<NGRAPH, 128, 0, stream>>>(h2, wbuf, pbuf, h3);
    k_clf3<<<1, 64, 0, stream>>>(h3, wbuf, pbuf, d_out, flags);
}